// Round 11
// baseline (190.864 us; speedup 1.0000x reference)
//
#include <hip/hip_runtime.h>
#include <math.h>

// ---------------------------------------------------------------------------
// A3C_LSTM_GA forward, batch=1.  R11: single 256-thread WG GRU scan.
// Empirical law from R1..R10: VGPR grant = 2048/(2*wavesPerWG); 256-thr WGs
// get demand-based allocation (R1: 108 granted, no spill; m08: ~450 OK).
// So: thread t holds ALL THREE gate-rows of unit t (384 weight VGPRs f16),
// full 256-dot per row, zero cross-lane reduction, 2 barriers/step.
//  K1 a3c_pre (582 blocks x 256):
//     b0 image MLP | b1-4 gates_h | b5 head-bias | b6-197 gi (f32)
//     b198-581 regw: gwh -> f16 fragment-major [f][t] (coalesced K2 load)
//  K2 a3c_scan (1 block x 256, waves_per_eu(1,1)): the scan + attn tail
//  K3 a3c_post (4 blocks x 256): LSTM -> h/c -> head atomicAdd partials
// ---------------------------------------------------------------------------

typedef __fp16 h2 __attribute__((ext_vector_type(2)));
typedef __fp16 h8 __attribute__((ext_vector_type(8)));
typedef float  f4 __attribute__((ext_vector_type(4)));

// ws float offsets
#define WS_IMG    0        // 128
#define WS_GATESH 128      // 1024
#define WS_FUSED  1152     // 256
#define WS_GI     1408     // 64*768 f32
#define WS_REGW   50560    // 98304 float slots (196608 f16)  end=148864

__device__ __forceinline__ float dot4(const float4 a, const float4 b){
  return a.x*b.x + a.y*b.y + a.z*b.z + a.w*b.w;
}
__device__ __forceinline__ float sigm(float x){ return 1.f/(1.f+expf(-x)); }

#define P0(v) __builtin_shufflevector(v,v,0,1)
#define P1(v) __builtin_shufflevector(v,v,2,3)
#define P2(v) __builtin_shufflevector(v,v,4,5)
#define P3(v) __builtin_shufflevector(v,v,6,7)
#define PK(a,b) __builtin_amdgcn_cvt_pkrtz(a,b)
#define FD(w,e,acc) __builtin_amdgcn_fdot2(w,e,acc,false)

// ------------------------------------------------------------------- K1
__global__ __launch_bounds__(256) void a3c_pre(
    const float* __restrict__ x,
    const float* __restrict__ i1w, const float* __restrict__ i1b,
    const float* __restrict__ i2w, const float* __restrict__ i2b,
    const float* __restrict__ i3w, const float* __restrict__ i3b,
    const float* __restrict__ hx,  const float* __restrict__ lwh,
    const float* __restrict__ lbh,
    const int*   __restrict__ tx,  const float* __restrict__ temb,
    const float* __restrict__ cw,  const float* __restrict__ cb,
    const float* __restrict__ acw, const float* __restrict__ acb,
    const int*   __restrict__ inst, const float* __restrict__ emb,
    const float* __restrict__ gwi,  const float* __restrict__ gbi,
    const float* __restrict__ gwh,
    float* __restrict__ ws, float* __restrict__ out)
{
  const int b = blockIdx.x;
  const int t = threadIdx.x;

  if (b == 0) {
    // image MLP 400 -> 128 -> 128 -> 128
    __shared__ __align__(16) float x_lds[400];
    __shared__ __align__(16) float h1[128];
    __shared__ __align__(16) float h2s[128];
    x_lds[t] = x[t];
    if (t < 144) x_lds[256+t] = x[256+t];
    __syncthreads();
    {
      const int o = t>>1, half = t&1;
      const float4* wr = (const float4*)(i1w + o*400 + half*200);
      const float4* xr = (const float4*)(x_lds + half*200);
      float acc = 0.f;
      #pragma unroll 5
      for (int k=0;k<50;++k) acc += dot4(wr[k], xr[k]);
      acc += __shfl_down(acc, 1, 2);
      if (half == 0) h1[o] = fmaxf(acc + i1b[o], 0.f);
    }
    __syncthreads();
    if (t < 128){
      const float4* wr = (const float4*)(i2w + t*128);
      const float4* h4 = (const float4*)h1;
      float acc = i2b[t];
      #pragma unroll 8
      for (int k=0;k<32;++k) acc += dot4(wr[k], h4[k]);
      h2s[t] = fmaxf(acc, 0.f);
    }
    __syncthreads();
    if (t < 128){
      const float4* wr = (const float4*)(i3w + t*128);
      const float4* h4 = (const float4*)h2s;
      float acc = i3b[t];
      #pragma unroll 8
      for (int k=0;k<32;++k) acc += dot4(wr[k], h4[k]);
      ws[WS_IMG + t] = fmaxf(acc, 0.f);
    }

  } else if (b <= 4) {
    // gates_h = hx @ lstm_wh.T + lstm_bh
    __shared__ __align__(16) float hx_lds[256];
    hx_lds[t] = hx[t];
    __syncthreads();
    const int R = (b-1)*256 + t;
    const float4* wr = (const float4*)(lwh + R*256);
    const float4* h4 = (const float4*)hx_lds;
    float acc = lbh[R];
    #pragma unroll 8
    for (int k=0;k<64;++k) acc += dot4(wr[k], h4[k]);
    ws[WS_GATESH + R] = acc;

  } else if (b == 5) {
    // out[0..4] = bias + time-embedding partial of heads
    if (t < 64){
      float tv = 0.f;
      if (t < 32) tv = temb[tx[0]*32 + t];
      #pragma unroll
      for (int o=0;o<5;++o){
        const float* wrow = (o==0) ? cw : (acw + (o-1)*288);
        float pr = (t < 32) ? tv*wrow[256+t] : 0.f;
        #pragma unroll
        for (int off=16; off; off>>=1) pr += __shfl_down(pr, off, 32);
        if (t == 0) out[o] = pr + ((o==0) ? cb[0] : acb[o-1]);
      }
    }

  } else if (b < 198) {
    // gi[s][row] (f32): 192 blocks x 256 = 49152 = 64*768
    const int idx = (b-6)*256 + t;
    const int s = idx / 768;
    const int r = idx - s*768;
    const float4* wr = (const float4*)(gwi + r*32);
    const float4* er = (const float4*)(emb + inst[s]*32);
    float acc = gbi[r];
    #pragma unroll
    for (int k=0;k<8;++k) acc += dot4(wr[k], er[k]);
    ws[WS_GI + idx] = acc;

  } else {
    // regw: 384 blocks x 256 = 98304 h2, fragment-major [f][tt][e2]:
    // fragment f = g*32+c (gate g, col-chunk c) of thread tt holds
    // gwh[g*256+tt][c*8 .. c*8+7];  h2 index d = (f*256+tt)*4 + e2
    const int d = (b-198)*256 + t;
    const int ft = d >> 2, e2 = d & 3;
    const int f = ft >> 8, tt = ft & 255;
    const int g = f >> 5,  c = f & 31;
    const int row = (g<<8) + tt;
    const int col = (c<<3) + (e2<<1);
    ((h2*)(ws + WS_REGW))[d] = PK(gwh[row*256+col], gwh[row*256+col+1]);
  }
}

// ------------------------------------------------------------------- K2
__global__ __launch_bounds__(256) __attribute__((amdgpu_waves_per_eu(1, 1)))
void a3c_scan(
    const float* __restrict__ gbh,
    const float* __restrict__ aw,  const float* __restrict__ ab,
    const float* __restrict__ lnw, const float* __restrict__ lnb,
    float* __restrict__ ws)
{
  const int t = threadIdx.x;
  __shared__ __align__(16) __fp16 h16[256];
  __shared__ __align__(16) float h32[256];
  __shared__ __align__(16) float f0[128];

  // ---- load this thread's 3 gate-rows: 96 coalesced f4 fragments (384 VGPR)
  f4 w0[32], w1[32], w2[32];
  {
    const f4* src = (const f4*)(ws + WS_REGW);
    #pragma unroll
    for (int c=0;c<32;++c) w0[c] = src[(c     )*256 + t];
    #pragma unroll
    for (int c=0;c<32;++c) w1[c] = src[(32 + c)*256 + t];
    #pragma unroll
    for (int c=0;c<32;++c) w2[c] = src[(64 + c)*256 + t];
    #pragma unroll
    for (int c=0;c<32;++c){
      asm volatile("" : "+v"(w0[c]));
      asm volatile("" : "+v"(w1[c]));
      asm volatile("" : "+v"(w2[c]));
    }
  }
  const float bh0 = gbh[t], bh1 = gbh[256+t], bh2 = gbh[512+t];
  h16[t] = (__fp16)0.f;
  h32[t] = 0.f;
  float g0 = ws[WS_GI + t];
  float g1 = ws[WS_GI + 256 + t];
  float g2 = ws[WS_GI + 512 + t];
  __syncthreads();

  // ---------------- 64-step scan: full 256-dot per gate row per thread
  for (int s=0; s<64; ++s){
    const int nx = (s<63) ? (s+1) : s;
    const float n0 = ws[WS_GI + nx*768 + t];
    const float n1 = ws[WS_GI + nx*768 + 256 + t];
    const float n2 = ws[WS_GI + nx*768 + 512 + t];

    float a0=0.f,b0=0.f, a1=0.f,b1=0.f, a2=0.f,b2=0.f;   // 6 indep chains
    #pragma unroll
    for (int c=0;c<32;++c){
      const h8 hv = *(const h8*)(h16 + (c<<3));   // broadcast ds_read_b128
      const h8 u0 = __builtin_bit_cast(h8, w0[c]);
      const h8 u1 = __builtin_bit_cast(h8, w1[c]);
      const h8 u2 = __builtin_bit_cast(h8, w2[c]);
      a0=FD(P0(u0),P0(hv),a0); b0=FD(P1(u0),P1(hv),b0);
      a0=FD(P2(u0),P2(hv),a0); b0=FD(P3(u0),P3(hv),b0);
      a1=FD(P0(u1),P0(hv),a1); b1=FD(P1(u1),P1(hv),b1);
      a1=FD(P2(u1),P2(hv),a1); b1=FD(P3(u1),P3(hv),b1);
      a2=FD(P0(u2),P0(hv),a2); b2=FD(P1(u2),P1(hv),b2);
      a2=FD(P2(u2),P2(hv),a2); b2=FD(P3(u2),P3(hv),b2);
    }
    const float sr = a0 + b0 + bh0;        // W_r.h + bh_r
    const float sz = a1 + b1 + bh1;        // W_z.h + bh_z
    const float sn = a2 + b2 + bh2;        // W_n.h + bh_n
    const float rr = sigm(g0 + sr);
    const float zz = sigm(g1 + sz);
    const float nn = tanhf(g2 + rr*sn);
    const float hv_ = (1.f - zz)*nn + zz*h32[t];
    __syncthreads();                        // all h16 reads complete
    h32[t] = hv_;
    h16[t] = (__fp16)hv_;
    g0 = n0; g1 = n1; g2 = n2;
    __syncthreads();
  }

  // ---------------- attention -> fuse -> lin (h_enc == h32)
  if (t < 128){
    const float4* wr = (const float4*)(aw + t*256);
    const float4* h4 = (const float4*)h32;
    float acc = ab[t];
    #pragma unroll 8
    for (int k=0;k<64;++k) acc += dot4(wr[k], h4[k]);
    f0[t] = ws[WS_IMG + t] * sigm(acc);
  }
  __syncthreads();
  {
    const float4* wr = (const float4*)(lnw + t*128);
    const float4* h4 = (const float4*)f0;
    float acc = lnb[t];
    #pragma unroll 8
    for (int k=0;k<32;++k) acc += dot4(wr[k], h4[k]);
    ws[WS_FUSED + t] = fmaxf(acc, 0.f);
  }
}

// ------------------------------------------------------------------- K3
__global__ __launch_bounds__(256) void a3c_post(
    const float* __restrict__ lwi, const float* __restrict__ lbi,
    const float* __restrict__ cx,
    const float* __restrict__ cw,  const float* __restrict__ acw,
    float* __restrict__ ws, float* __restrict__ out)
{
  const int p = blockIdx.x;            // 0..3, owns 64 LSTM units
  const int t = threadIdx.x;
  __shared__ __align__(16) float fused_lds[256];
  __shared__ float gv[256];
  __shared__ float hh[64];
  fused_lds[t] = ws[WS_FUSED + t];
  __syncthreads();
  const int g = t>>6, ul = t&63;
  const int R = (g<<8) + p*64 + ul;
  const float4* wr = (const float4*)(lwi + R*256);
  const float4* f4p = (const float4*)fused_lds;
  float acc = ws[WS_GATESH + R] + lbi[R];
  #pragma unroll 8
  for (int k=0;k<64;++k) acc += dot4(wr[k], f4p[k]);
  gv[t] = acc;
  __syncthreads();
  if (t < 64){
    const int u2 = p*64 + t;
    const float iv = gv[t], fv = gv[64+t], gg = gv[128+t], ov = gv[192+t];
    const float c = sigm(fv)*cx[u2] + sigm(iv)*tanhf(gg);
    const float h = sigm(ov)*tanhf(c);
    out[5   + u2] = h;
    out[261 + u2] = c;
    hh[t] = h;
  }
  __syncthreads();
  if (t < 64){
    #pragma unroll
    for (int o=0;o<5;++o){
      const float* wrow = (o==0) ? cw : (acw + (o-1)*288);
      float pr = hh[t]*wrow[p*64 + t];
      #pragma unroll
      for (int off=32; off; off>>=1) pr += __shfl_down(pr, off, 64);
      if (t == 0) atomicAdd(out + o, pr);
    }
  }
}

extern "C" void kernel_launch(void* const* d_in, const int* in_sizes, int n_in,
                              void* d_out, int out_size, void* d_ws, size_t ws_size,
                              hipStream_t stream) {
  (void)in_sizes; (void)n_in; (void)out_size; (void)ws_size;
  const float* x    = (const float*)d_in[0];
  const int*   inst = (const int*)  d_in[1];
  const int*   tx   = (const int*)  d_in[2];
  const float* hx   = (const float*)d_in[3];
  const float* cx   = (const float*)d_in[4];
  const float* i1w  = (const float*)d_in[5];
  const float* i1b  = (const float*)d_in[6];
  const float* i2w  = (const float*)d_in[7];
  const float* i2b  = (const float*)d_in[8];
  const float* i3w  = (const float*)d_in[9];
  const float* i3b  = (const float*)d_in[10];
  const float* emb  = (const float*)d_in[11];
  const float* gwi  = (const float*)d_in[12];
  const float* gwh  = (const float*)d_in[13];
  const float* gbi  = (const float*)d_in[14];
  const float* gbh  = (const float*)d_in[15];
  const float* aw   = (const float*)d_in[16];
  const float* ab   = (const float*)d_in[17];
  const float* temb = (const float*)d_in[18];
  const float* lnw  = (const float*)d_in[19];
  const float* lnb  = (const float*)d_in[20];
  const float* lwi  = (const float*)d_in[21];
  const float* lwh  = (const float*)d_in[22];
  const float* lbi  = (const float*)d_in[23];
  const float* lbh  = (const float*)d_in[24];
  const float* cw   = (const float*)d_in[25];
  const float* cb   = (const float*)d_in[26];
  const float* acw  = (const float*)d_in[27];
  const float* acb  = (const float*)d_in[28];
  float* ws  = (float*)d_ws;
  float* out = (float*)d_out;

  a3c_pre <<<582, 256, 0, stream>>>(x, i1w, i1b, i2w, i2b, i3w, i3b,
                                    hx, lwh, lbh, tx, temb, cw, cb, acw, acb,
                                    inst, emb, gwi, gbi, gwh, ws, out);
  a3c_scan<<<1, 256, 0, stream>>>(gbh, aw, ab, lnw, lnb, ws);
  a3c_post<<<4, 256, 0, stream>>>(lwi, lbi, cx, cw, acw, ws, out);
}

// Round 12
// 181.658 us; speedup vs baseline: 1.0507x; 1.0507x over previous
//
#include <hip/hip_runtime.h>
#include <math.h>

// ---------------------------------------------------------------------------
// A3C_LSTM_GA forward, batch=1.  R12: single 256-thread-WG GRU scan, hybrid
// register+LDS weights sized to the measured allocation law
//   grant = min(256, 2048/(2*wavesPerWG))  ->  usable RF/CU = 256 KB.
// Thread t owns unit t's 3 gate rows.  Cols [0,152) in 228 pinned VGPRs;
// cols [152,256) in LDS col-major chunks [c8][row] (conflict-free b128,
// no padding, 156 KB).  Gate math thread-local; 2 barriers/step.
//  K1 a3c_pre (582 blocks x 256): b0 image MLP | b1-4 gates_h | b5 head-bias
//     b6-197 gi (f32) | b198-425 regw pack | b426-581 ldsw pack
//  K2 a3c_scan (1 block x 256): scan + attention/fuse/lin tail
//  K3 a3c_post (4 blocks x 256): LSTM -> h/c -> head atomicAdd partials
// ---------------------------------------------------------------------------

typedef __fp16 h2 __attribute__((ext_vector_type(2)));
typedef __fp16 h8 __attribute__((ext_vector_type(8)));
typedef float  f4 __attribute__((ext_vector_type(4)));

// ws float offsets
#define WS_IMG    0        // 128
#define WS_GATESH 128      // 1024
#define WS_FUSED  1152     // 256
#define WS_GI     1408     // 64*768 f32                      end 50560
#define WS_REGW   50560    // 58368 h2 = 29184 f32 slots      end 79744
#define WS_LDSW   79744    // 39936 h2 = 19968 f32 slots      end 99712

__device__ __forceinline__ float dot4(const float4 a, const float4 b){
  return a.x*b.x + a.y*b.y + a.z*b.z + a.w*b.w;
}
__device__ __forceinline__ float sigm(float x){ return 1.f/(1.f+expf(-x)); }

#define P0(v) __builtin_shufflevector(v,v,0,1)
#define P1(v) __builtin_shufflevector(v,v,2,3)
#define P2(v) __builtin_shufflevector(v,v,4,5)
#define P3(v) __builtin_shufflevector(v,v,6,7)
#define PK(a,b) __builtin_amdgcn_cvt_pkrtz(a,b)
#define FD(w,e,acc) __builtin_amdgcn_fdot2(w,e,acc,false)

// ------------------------------------------------------------------- K1
__global__ __launch_bounds__(256) void a3c_pre(
    const float* __restrict__ x,
    const float* __restrict__ i1w, const float* __restrict__ i1b,
    const float* __restrict__ i2w, const float* __restrict__ i2b,
    const float* __restrict__ i3w, const float* __restrict__ i3b,
    const float* __restrict__ hx,  const float* __restrict__ lwh,
    const float* __restrict__ lbh,
    const int*   __restrict__ tx,  const float* __restrict__ temb,
    const float* __restrict__ cw,  const float* __restrict__ cb,
    const float* __restrict__ acw, const float* __restrict__ acb,
    const int*   __restrict__ inst, const float* __restrict__ emb,
    const float* __restrict__ gwi,  const float* __restrict__ gbi,
    const float* __restrict__ gwh,
    float* __restrict__ ws, float* __restrict__ out)
{
  const int b = blockIdx.x;
  const int t = threadIdx.x;

  if (b == 0) {
    // image MLP 400 -> 128 -> 128 -> 128
    __shared__ __align__(16) float x_lds[400];
    __shared__ __align__(16) float h1[128];
    __shared__ __align__(16) float h2s[128];
    x_lds[t] = x[t];
    if (t < 144) x_lds[256+t] = x[256+t];
    __syncthreads();
    {
      const int o = t>>1, half = t&1;
      const float4* wr = (const float4*)(i1w + o*400 + half*200);
      const float4* xr = (const float4*)(x_lds + half*200);
      float acc = 0.f;
      #pragma unroll 5
      for (int k=0;k<50;++k) acc += dot4(wr[k], xr[k]);
      acc += __shfl_down(acc, 1, 2);
      if (half == 0) h1[o] = fmaxf(acc + i1b[o], 0.f);
    }
    __syncthreads();
    if (t < 128){
      const float4* wr = (const float4*)(i2w + t*128);
      const float4* h4 = (const float4*)h1;
      float acc = i2b[t];
      #pragma unroll 8
      for (int k=0;k<32;++k) acc += dot4(wr[k], h4[k]);
      h2s[t] = fmaxf(acc, 0.f);
    }
    __syncthreads();
    if (t < 128){
      const float4* wr = (const float4*)(i3w + t*128);
      const float4* h4 = (const float4*)h2s;
      float acc = i3b[t];
      #pragma unroll 8
      for (int k=0;k<32;++k) acc += dot4(wr[k], h4[k]);
      ws[WS_IMG + t] = fmaxf(acc, 0.f);
    }

  } else if (b <= 4) {
    // gates_h = hx @ lstm_wh.T + lstm_bh
    __shared__ __align__(16) float hx_lds[256];
    hx_lds[t] = hx[t];
    __syncthreads();
    const int R = (b-1)*256 + t;
    const float4* wr = (const float4*)(lwh + R*256);
    const float4* h4 = (const float4*)hx_lds;
    float acc = lbh[R];
    #pragma unroll 8
    for (int k=0;k<64;++k) acc += dot4(wr[k], h4[k]);
    ws[WS_GATESH + R] = acc;

  } else if (b == 5) {
    // out[0..4] = bias + time-embedding partial of heads
    if (t < 64){
      float tv = 0.f;
      if (t < 32) tv = temb[tx[0]*32 + t];
      #pragma unroll
      for (int o=0;o<5;++o){
        const float* wrow = (o==0) ? cw : (acw + (o-1)*288);
        float pr = (t < 32) ? tv*wrow[256+t] : 0.f;
        #pragma unroll
        for (int off=16; off; off>>=1) pr += __shfl_down(pr, off, 32);
        if (t == 0) out[o] = pr + ((o==0) ? cb[0] : acb[o-1]);
      }
    }

  } else if (b < 198) {
    // gi[s][row] (f32): 192 blocks x 256 = 49152 = 64*768
    const int idx = (b-6)*256 + t;
    const int s = idx / 768;
    const int r = idx - s*768;
    const float4* wr = (const float4*)(gwi + r*32);
    const float4* er = (const float4*)(emb + inst[s]*32);
    float acc = gbi[r];
    #pragma unroll
    for (int k=0;k<8;++k) acc += dot4(wr[k], er[k]);
    ws[WS_GI + idx] = acc;

  } else if (b < 426) {
    // regw: fragment-major.  frag f = g*19+c (gate g, chunk c) of thread tt
    // holds cols [c*8, c*8+8) of row g*256+tt.  h2 idx d = (f*256+tt)*4+e2
    const int d = (b-198)*256 + t;
    const int ft = d >> 2, e2 = d & 3;
    const int f = ft >> 8, tt = ft & 255;
    const int g = f / 19, c = f - g*19;
    const int row = (g<<8) + tt;
    const int col = (c<<3) + (e2<<1);
    ((h2*)(ws + WS_REGW))[d] = PK(gwh[row*256+col], gwh[row*256+col+1]);

  } else {
    // ldsw: col-major chunks [c8][row]: cols 152+c8*8+[0,8) of row.
    // h2 idx d = ((c8*768+row)*4 + e2)
    const int d = (b-426)*256 + t;
    const int ft = d >> 2, e2 = d & 3;
    const int c8 = ft / 768, row = ft - c8*768;
    const int col = 152 + (c8<<3) + (e2<<1);
    ((h2*)(ws + WS_LDSW))[d] = PK(gwh[row*256+col], gwh[row*256+col+1]);
  }
}

// ------------------------------------------------------------------- K2
__global__ __launch_bounds__(256) void a3c_scan(
    const float* __restrict__ gbh,
    const float* __restrict__ aw,  const float* __restrict__ ab,
    const float* __restrict__ lnw, const float* __restrict__ lnb,
    float* __restrict__ ws)
{
  const int t = threadIdx.x;
  __shared__ __align__(16) __fp16 lw16[13*768*8];   // 159744 B
  __shared__ __align__(16) __fp16 h16[256];
  __shared__ __align__(16) float h32[256];
  __shared__ __align__(16) float f0[128];

  // stage LDS weight chunk (linear coalesced copy: 39 float4 per thread)
  {
    const float4* src = (const float4*)(ws + WS_LDSW);
    float4* dst = (float4*)lw16;
    #pragma unroll
    for (int n=0;n<39;++n) dst[n*256+t] = src[n*256+t];
  }
  // register fragments: cols [0,152) of rows t, 256+t, 512+t  (228 VGPRs)
  f4 wr_[19], wz_[19], wn_[19];
  {
    const f4* src = (const f4*)(ws + WS_REGW);
    #pragma unroll
    for (int c=0;c<19;++c) wr_[c] = src[(c     )*256 + t];
    #pragma unroll
    for (int c=0;c<19;++c) wz_[c] = src[(19 + c)*256 + t];
    #pragma unroll
    for (int c=0;c<19;++c) wn_[c] = src[(38 + c)*256 + t];
    #pragma unroll
    for (int c=0;c<19;++c){
      asm volatile("" : "+v"(wr_[c]));
      asm volatile("" : "+v"(wz_[c]));
      asm volatile("" : "+v"(wn_[c]));
    }
  }
  const float bh0 = gbh[t], bh1 = gbh[256+t], bh2 = gbh[512+t];
  float g0 = ws[WS_GI + t] + bh0;        // fold bias into gi stream:
  float g1 = ws[WS_GI + 256 + t];        // r uses g0 + a0 (bh pre-added)
  float g2 = ws[WS_GI + 512 + t];
  h16[t] = (__fp16)0.f;
  h32[t] = 0.f;
  __syncthreads();

  // ---------------- 64-step scan ----------------
  for (int s=0;s<64;++s){
    const int nx = (s<63) ? (s+1) : s;
    const float n0 = ws[WS_GI + nx*768 + t] + bh0;
    const float n1 = ws[WS_GI + nx*768 + 256 + t];
    const float n2 = ws[WS_GI + nx*768 + 512 + t];

    float a0=0.f, a1=0.f, a2=0.f;
    // reg part: cols [0,152)
    #pragma unroll
    for (int c=0;c<19;++c){
      const h8 hv = *(const h8*)(h16 + (c<<3));       // broadcast b128
      const h8 u0 = __builtin_bit_cast(h8, wr_[c]);
      const h8 u1 = __builtin_bit_cast(h8, wz_[c]);
      const h8 u2 = __builtin_bit_cast(h8, wn_[c]);
      a0=FD(P0(u0),P0(hv),a0); a0=FD(P1(u0),P1(hv),a0);
      a0=FD(P2(u0),P2(hv),a0); a0=FD(P3(u0),P3(hv),a0);
      a1=FD(P0(u1),P0(hv),a1); a1=FD(P1(u1),P1(hv),a1);
      a1=FD(P2(u1),P2(hv),a1); a1=FD(P3(u1),P3(hv),a1);
      a2=FD(P0(u2),P0(hv),a2); a2=FD(P1(u2),P1(hv),a2);
      a2=FD(P2(u2),P2(hv),a2); a2=FD(P3(u2),P3(hv),a2);
    }
    // LDS part: cols [152,256), col-major chunks -> conflict-free b128
    #pragma unroll
    for (int c8=0;c8<13;++c8){
      const h8 hv = *(const h8*)(h16 + 152 + (c8<<3)); // broadcast
      const h8 u0 = *(const h8*)(lw16 + ((c8*768 +        t)<<3));
      const h8 u1 = *(const h8*)(lw16 + ((c8*768 + 256 +  t)<<3));
      const h8 u2 = *(const h8*)(lw16 + ((c8*768 + 512 +  t)<<3));
      a0=FD(P0(u0),P0(hv),a0); a0=FD(P1(u0),P1(hv),a0);
      a0=FD(P2(u0),P2(hv),a0); a0=FD(P3(u0),P3(hv),a0);
      a1=FD(P0(u1),P0(hv),a1); a1=FD(P1(u1),P1(hv),a1);
      a1=FD(P2(u1),P2(hv),a1); a1=FD(P3(u1),P3(hv),a1);
      a2=FD(P0(u2),P0(hv),a2); a2=FD(P1(u2),P1(hv),a2);
      a2=FD(P2(u2),P2(hv),a2); a2=FD(P3(u2),P3(hv),a2);
    }

    const float rr = sigm(g0 + a0);                    // bh0 folded in g0
    const float zz = sigm(g1 + a1 + bh1);
    const float nn = tanhf(g2 + rr*(a2 + bh2));
    const float hv_ = (1.f - zz)*nn + zz*h32[t];
    __syncthreads();                 // all reads of h16 complete
    h32[t] = hv_;
    h16[t] = (__fp16)hv_;
    g0 = n0; g1 = n1; g2 = n2;
    __syncthreads();
  }

  // ---------------- attention -> fuse -> lin (h_enc == h32)
  if (t < 128){
    const float4* wr = (const float4*)(aw + t*256);
    const float4* h4 = (const float4*)h32;
    float acc = ab[t];
    #pragma unroll 8
    for (int k=0;k<64;++k) acc += dot4(wr[k], h4[k]);
    f0[t] = ws[WS_IMG + t] * sigm(acc);
  }
  __syncthreads();
  {
    const float4* wr = (const float4*)(lnw + t*128);
    const float4* h4 = (const float4*)f0;
    float acc = lnb[t];
    #pragma unroll 8
    for (int k=0;k<32;++k) acc += dot4(wr[k], h4[k]);
    ws[WS_FUSED + t] = fmaxf(acc, 0.f);
  }
}

// ------------------------------------------------------------------- K3
__global__ __launch_bounds__(256) void a3c_post(
    const float* __restrict__ lwi, const float* __restrict__ lbi,
    const float* __restrict__ cx,
    const float* __restrict__ cw,  const float* __restrict__ acw,
    float* __restrict__ ws, float* __restrict__ out)
{
  const int p = blockIdx.x;            // 0..3, owns 64 LSTM units
  const int t = threadIdx.x;
  __shared__ __align__(16) float fused_lds[256];
  __shared__ float gv[256];
  __shared__ float hh[64];
  fused_lds[t] = ws[WS_FUSED + t];
  __syncthreads();
  const int g = t>>6, ul = t&63;
  const int R = (g<<8) + p*64 + ul;
  const float4* wr = (const float4*)(lwi + R*256);
  const float4* f4p = (const float4*)fused_lds;
  float acc = ws[WS_GATESH + R] + lbi[R];
  #pragma unroll 8
  for (int k=0;k<64;++k) acc += dot4(wr[k], f4p[k]);
  gv[t] = acc;
  __syncthreads();
  if (t < 64){
    const int u2 = p*64 + t;
    const float iv = gv[t], fv = gv[64+t], gg = gv[128+t], ov = gv[192+t];
    const float c = sigm(fv)*cx[u2] + sigm(iv)*tanhf(gg);
    const float h = sigm(ov)*tanhf(c);
    out[5   + u2] = h;
    out[261 + u2] = c;
    hh[t] = h;
  }
  __syncthreads();
  if (t < 64){
    #pragma unroll
    for (int o=0;o<5;++o){
      const float* wrow = (o==0) ? cw : (acw + (o-1)*288);
      float pr = hh[t]*wrow[p*64 + t];
      #pragma unroll
      for (int off=32; off; off>>=1) pr += __shfl_down(pr, off, 64);
      if (t == 0) atomicAdd(out + o, pr);
    }
  }
}

extern "C" void kernel_launch(void* const* d_in, const int* in_sizes, int n_in,
                              void* d_out, int out_size, void* d_ws, size_t ws_size,
                              hipStream_t stream) {
  (void)in_sizes; (void)n_in; (void)out_size; (void)ws_size;
  const float* x    = (const float*)d_in[0];
  const int*   inst = (const int*)  d_in[1];
  const int*   tx   = (const int*)  d_in[2];
  const float* hx   = (const float*)d_in[3];
  const float* cx   = (const float*)d_in[4];
  const float* i1w  = (const float*)d_in[5];
  const float* i1b  = (const float*)d_in[6];
  const float* i2w  = (const float*)d_in[7];
  const float* i2b  = (const float*)d_in[8];
  const float* i3w  = (const float*)d_in[9];
  const float* i3b  = (const float*)d_in[10];
  const float* emb  = (const float*)d_in[11];
  const float* gwi  = (const float*)d_in[12];
  const float* gwh  = (const float*)d_in[13];
  const float* gbi  = (const float*)d_in[14];
  const float* gbh  = (const float*)d_in[15];
  const float* aw   = (const float*)d_in[16];
  const float* ab   = (const float*)d_in[17];
  const float* temb = (const float*)d_in[18];
  const float* lnw  = (const float*)d_in[19];
  const float* lnb  = (const float*)d_in[20];
  const float* lwi  = (const float*)d_in[21];
  const float* lwh  = (const float*)d_in[22];
  const float* lbi  = (const float*)d_in[23];
  const float* lbh  = (const float*)d_in[24];
  const float* cw   = (const float*)d_in[25];
  const float* cb   = (const float*)d_in[26];
  const float* acw  = (const float*)d_in[27];
  const float* acb  = (const float*)d_in[28];
  float* ws  = (float*)d_ws;
  float* out = (float*)d_out;

  a3c_pre <<<582, 256, 0, stream>>>(x, i1w, i1b, i2w, i2b, i3w, i3b,
                                    hx, lwh, lbh, tx, temb, cw, cb, acw, acb,
                                    inst, emb, gwi, gbi, gwh, ws, out);
  a3c_scan<<<1, 256, 0, stream>>>(gbh, aw, ab, lnw, lnb, ws);
  a3c_post<<<4, 256, 0, stream>>>(lwi, lbi, cx, cw, acw, ws, out);
}

// Round 13
// 156.275 us; speedup vs baseline: 1.2213x; 1.1624x over previous
//
#include <hip/hip_runtime.h>
#include <math.h>

// ---------------------------------------------------------------------------
// A3C_LSTM_GA forward, batch=1.  R13: single 256-thread-WG GRU scan with the
// weight matrix held as MFMA A-fragments across the UNIFIED VGPR+AGPR file
// (512 regs/wave at 1 wave/SIMD; AGPRs are legal MFMA operands on gfx950).
// Wave w owns gate-rows [192w,192w+192) as 96 named h8 fragments (384 regs).
// Per step: per-K B fragment (h in col 0 — R6's shared-B bug FIXED),
// 96 mfma_f32_16x16x32_f16 in 12 chains, D col-0 scatter, thread-local gate
// math, 2 barriers.  No cross-WG sync anywhere.
//  K1 a3c_pre (582 blocks x 256): b0 image MLP | b1-4 gates_h | b5 head-bias
//     b6-197 gi (f32) | b198-581 regw: gwh -> f16 (RTN) fragment-major layout
//  K2 a3c_scan (1 block x 256): MFMA scan + attention/fuse/lin tail
//  K3 a3c_post (4 blocks x 256): LSTM -> h/c -> head atomicAdd partials
// ---------------------------------------------------------------------------

typedef __fp16 h2 __attribute__((ext_vector_type(2)));
typedef __fp16 h8 __attribute__((ext_vector_type(8)));
typedef float  f4 __attribute__((ext_vector_type(4)));

// ws float offsets
#define WS_IMG    0        // 128
#define WS_GATESH 128      // 1024
#define WS_FUSED  1152     // 256
#define WS_GI     1408     // 64*768 f32                       end 50560
#define WS_REGW   50560    // 98304 h2 = 49152 f32 slots       end 99712

__device__ __forceinline__ float dot4(const float4 a, const float4 b){
  return a.x*b.x + a.y*b.y + a.z*b.z + a.w*b.w;
}
__device__ __forceinline__ float sigm(float x){ return 1.f/(1.f+expf(-x)); }

// ------------------------------------------------------------------- K1
__global__ __launch_bounds__(256) void a3c_pre(
    const float* __restrict__ x,
    const float* __restrict__ i1w, const float* __restrict__ i1b,
    const float* __restrict__ i2w, const float* __restrict__ i2b,
    const float* __restrict__ i3w, const float* __restrict__ i3b,
    const float* __restrict__ hx,  const float* __restrict__ lwh,
    const float* __restrict__ lbh,
    const int*   __restrict__ tx,  const float* __restrict__ temb,
    const float* __restrict__ cw,  const float* __restrict__ cb,
    const float* __restrict__ acw, const float* __restrict__ acb,
    const int*   __restrict__ inst, const float* __restrict__ emb,
    const float* __restrict__ gwi,  const float* __restrict__ gbi,
    const float* __restrict__ gwh,
    float* __restrict__ ws, float* __restrict__ out)
{
  const int b = blockIdx.x;
  const int t = threadIdx.x;

  if (b == 0) {
    // image MLP 400 -> 128 -> 128 -> 128
    __shared__ __align__(16) float x_lds[400];
    __shared__ __align__(16) float h1[128];
    __shared__ __align__(16) float h2s[128];
    x_lds[t] = x[t];
    if (t < 144) x_lds[256+t] = x[256+t];
    __syncthreads();
    {
      const int o = t>>1, half = t&1;
      const float4* wr = (const float4*)(i1w + o*400 + half*200);
      const float4* xr = (const float4*)(x_lds + half*200);
      float acc = 0.f;
      #pragma unroll 5
      for (int k=0;k<50;++k) acc += dot4(wr[k], xr[k]);
      acc += __shfl_down(acc, 1, 2);
      if (half == 0) h1[o] = fmaxf(acc + i1b[o], 0.f);
    }
    __syncthreads();
    if (t < 128){
      const float4* wr = (const float4*)(i2w + t*128);
      const float4* h4 = (const float4*)h1;
      float acc = i2b[t];
      #pragma unroll 8
      for (int k=0;k<32;++k) acc += dot4(wr[k], h4[k]);
      h2s[t] = fmaxf(acc, 0.f);
    }
    __syncthreads();
    if (t < 128){
      const float4* wr = (const float4*)(i3w + t*128);
      const float4* h4 = (const float4*)h2s;
      float acc = i3b[t];
      #pragma unroll 8
      for (int k=0;k<32;++k) acc += dot4(wr[k], h4[k]);
      ws[WS_IMG + t] = fmaxf(acc, 0.f);
    }

  } else if (b <= 4) {
    // gates_h = hx @ lstm_wh.T + lstm_bh
    __shared__ __align__(16) float hx_lds[256];
    hx_lds[t] = hx[t];
    __syncthreads();
    const int R = (b-1)*256 + t;
    const float4* wr = (const float4*)(lwh + R*256);
    const float4* h4 = (const float4*)hx_lds;
    float acc = lbh[R];
    #pragma unroll 8
    for (int k=0;k<64;++k) acc += dot4(wr[k], h4[k]);
    ws[WS_GATESH + R] = acc;

  } else if (b == 5) {
    // out[0..4] = bias + time-embedding partial of heads
    if (t < 64){
      float tv = 0.f;
      if (t < 32) tv = temb[tx[0]*32 + t];
      #pragma unroll
      for (int o=0;o<5;++o){
        const float* wrow = (o==0) ? cw : (acw + (o-1)*288);
        float pr = (t < 32) ? tv*wrow[256+t] : 0.f;
        #pragma unroll
        for (int off=16; off; off>>=1) pr += __shfl_down(pr, off, 32);
        if (t == 0) out[o] = pr + ((o==0) ? cb[0] : acb[o-1]);
      }
    }

  } else if (b < 198) {
    // gi[s][row] (f32): 192 blocks x 256 = 49152 = 64*768
    const int idx = (b-6)*256 + t;
    const int s = idx / 768;
    const int r = idx - s*768;
    const float4* wr = (const float4*)(gwi + r*32);
    const float4* er = (const float4*)(emb + inst[s]*32);
    float acc = gbi[r];
    #pragma unroll
    for (int k=0;k<8;++k) acc += dot4(wr[k], er[k]);
    ws[WS_GI + idx] = acc;

  } else {
    // regw: MFMA fragment-major, RTN pack.
    // h2 index d: ft=d>>2 (frag-thread), e2=d&3; f=ft>>8 (0..95), tt=ft&255;
    // T=f>>3, K=f&7; wave=tt>>6, lane=tt&63, arow=lane&15, kgrp=lane>>4;
    // row = wave*192 + T*16 + arow ; col = K*32 + kgrp*8 + e2*2
    const int d  = (b-198)*256 + t;
    const int ft = d >> 2, e2 = d & 3;
    const int f  = ft >> 8, tt = ft & 255;
    const int T  = f >> 3,  K  = f & 7;
    const int wv = tt >> 6, lane = tt & 63;
    const int row = wv*192 + T*16 + (lane & 15);
    const int col = K*32 + (lane >> 4)*8 + e2*2;
    h2 v;
    v[0] = (__fp16)gwh[row*256 + col];      // RTN rounding
    v[1] = (__fp16)gwh[row*256 + col + 1];
    ((h2*)(ws + WS_REGW))[d] = v;
  }
}

// ------------------------------------------------------------------- K2
__global__ __launch_bounds__(256) void a3c_scan(
    const float* __restrict__ gbh,
    const float* __restrict__ aw,  const float* __restrict__ ab,
    const float* __restrict__ lnw, const float* __restrict__ lnb,
    float* __restrict__ ws)
{
  const int t = threadIdx.x;
  const int w = t >> 6, lane = t & 63;
  const int arow = lane & 15;
  const int kgrp = lane >> 4;
  const int koff = kgrp * 8;

  __shared__ __align__(16) __fp16 h16[256];
  __shared__ __align__(16) float h32[256];
  __shared__ __align__(16) float acc_lds[768];
  __shared__ __align__(16) float f0[128];

  // ---- load 96 MFMA A-fragments (384 regs across unified VGPR+AGPR file)
  const h8* src = (const h8*)(ws + WS_REGW);
  #define LDT(T) \
    const h8 F##T##_0=src[((T)*8+0)*256+t], F##T##_1=src[((T)*8+1)*256+t], \
             F##T##_2=src[((T)*8+2)*256+t], F##T##_3=src[((T)*8+3)*256+t], \
             F##T##_4=src[((T)*8+4)*256+t], F##T##_5=src[((T)*8+5)*256+t], \
             F##T##_6=src[((T)*8+6)*256+t], F##T##_7=src[((T)*8+7)*256+t];
  LDT(0) LDT(1) LDT(2) LDT(3) LDT(4) LDT(5)
  LDT(6) LDT(7) LDT(8) LDT(9) LDT(10) LDT(11)
  #undef LDT

  const float bh0 = gbh[t], bh1 = gbh[256+t], bh2 = gbh[512+t];
  float g0 = ws[WS_GI + t] + bh0;
  float g1 = ws[WS_GI + 256 + t];
  float g2 = ws[WS_GI + 512 + t];
  h16[t] = (__fp16)0.f;
  h32[t] = 0.f;
  __syncthreads();

  const h8 hz = {0,0,0,0,0,0,0,0};

  // ---------------- 64-step scan ----------------
  for (int s=0;s<64;++s){
    const int nx = (s<63) ? (s+1) : s;
    const float n0 = ws[WS_GI + nx*768 + t] + bh0;
    const float n1 = ws[WS_GI + nx*768 + 256 + t];
    const float n2 = ws[WS_GI + nx*768 + 512 + t];

    f4 d0={0,0,0,0},d1={0,0,0,0},d2={0,0,0,0},d3={0,0,0,0};
    f4 d4={0,0,0,0},d5={0,0,0,0},d6={0,0,0,0},d7={0,0,0,0};
    f4 d8={0,0,0,0},d9={0,0,0,0},d10={0,0,0,0},d11={0,0,0,0};

    // per-K B fragment: B[k][0] = h[K*32 + k], other cols 0
    #define MMK(K) { \
      const h8 hvk = *(const h8*)(h16 + (K)*32 + koff); \
      const h8 bfk = (arow == 0) ? hvk : hz; \
      d0  = __builtin_amdgcn_mfma_f32_16x16x32_f16(F0_##K,  bfk, d0, 0,0,0); \
      d1  = __builtin_amdgcn_mfma_f32_16x16x32_f16(F1_##K,  bfk, d1, 0,0,0); \
      d2  = __builtin_amdgcn_mfma_f32_16x16x32_f16(F2_##K,  bfk, d2, 0,0,0); \
      d3  = __builtin_amdgcn_mfma_f32_16x16x32_f16(F3_##K,  bfk, d3, 0,0,0); \
      d4  = __builtin_amdgcn_mfma_f32_16x16x32_f16(F4_##K,  bfk, d4, 0,0,0); \
      d5  = __builtin_amdgcn_mfma_f32_16x16x32_f16(F5_##K,  bfk, d5, 0,0,0); \
      d6  = __builtin_amdgcn_mfma_f32_16x16x32_f16(F6_##K,  bfk, d6, 0,0,0); \
      d7  = __builtin_amdgcn_mfma_f32_16x16x32_f16(F7_##K,  bfk, d7, 0,0,0); \
      d8  = __builtin_amdgcn_mfma_f32_16x16x32_f16(F8_##K,  bfk, d8, 0,0,0); \
      d9  = __builtin_amdgcn_mfma_f32_16x16x32_f16(F9_##K,  bfk, d9, 0,0,0); \
      d10 = __builtin_amdgcn_mfma_f32_16x16x32_f16(F10_##K, bfk, d10,0,0,0); \
      d11 = __builtin_amdgcn_mfma_f32_16x16x32_f16(F11_##K, bfk, d11,0,0,0); }
    MMK(0) MMK(1) MMK(2) MMK(3) MMK(4) MMK(5) MMK(6) MMK(7)
    #undef MMK

    // D col 0 lives in lanes arow==0: D[row = kgrp*4 + reg][0]
    if (arow == 0){
      const int rb = w*192 + kgrp*4;
      *(f4*)(acc_lds + rb +   0) = d0;
      *(f4*)(acc_lds + rb +  16) = d1;
      *(f4*)(acc_lds + rb +  32) = d2;
      *(f4*)(acc_lds + rb +  48) = d3;
      *(f4*)(acc_lds + rb +  64) = d4;
      *(f4*)(acc_lds + rb +  80) = d5;
      *(f4*)(acc_lds + rb +  96) = d6;
      *(f4*)(acc_lds + rb + 112) = d7;
      *(f4*)(acc_lds + rb + 128) = d8;
      *(f4*)(acc_lds + rb + 144) = d9;
      *(f4*)(acc_lds + rb + 160) = d10;
      *(f4*)(acc_lds + rb + 176) = d11;
    }
    __syncthreads();
    {
      const float rr = sigm(g0 + acc_lds[t]);                 // bh0 in g0
      const float zz = sigm(g1 + acc_lds[256 + t] + bh1);
      const float nn = tanhf(g2 + rr*(acc_lds[512 + t] + bh2));
      const float hv_ = (1.f - zz)*nn + zz*h32[t];
      h32[t] = hv_;
      h16[t] = (__fp16)hv_;
      g0 = n0; g1 = n1; g2 = n2;
    }
    __syncthreads();
  }

  // ---------------- attention -> fuse -> lin (h_enc == h32)
  if (t < 128){
    const float4* wr = (const float4*)(aw + t*256);
    const float4* h4 = (const float4*)h32;
    float acc = ab[t];
    #pragma unroll 8
    for (int k=0;k<64;++k) acc += dot4(wr[k], h4[k]);
    f0[t] = ws[WS_IMG + t] * sigm(acc);
  }
  __syncthreads();
  {
    const float4* wr = (const float4*)(lnw + t*128);
    const float4* h4 = (const float4*)f0;
    float acc = lnb[t];
    #pragma unroll 8
    for (int k=0;k<32;++k) acc += dot4(wr[k], h4[k]);
    ws[WS_FUSED + t] = fmaxf(acc, 0.f);
  }
}

// ------------------------------------------------------------------- K3
__global__ __launch_bounds__(256) void a3c_post(
    const float* __restrict__ lwi, const float* __restrict__ lbi,
    const float* __restrict__ cx,
    const float* __restrict__ cw,  const float* __restrict__ acw,
    float* __restrict__ ws, float* __restrict__ out)
{
  const int p = blockIdx.x;            // 0..3, owns 64 LSTM units
  const int t = threadIdx.x;
  __shared__ __align__(16) float fused_lds[256];
  __shared__ float gv[256];
  __shared__ float hh[64];
  fused_lds[t] = ws[WS_FUSED + t];
  __syncthreads();
  const int g = t>>6, ul = t&63;
  const int R = (g<<8) + p*64 + ul;
  const float4* wr = (const float4*)(lwi + R*256);
  const float4* f4p = (const float4*)fused_lds;
  float acc = ws[WS_GATESH + R] + lbi[R];
  #pragma unroll 8
  for (int k=0;k<64;++k) acc += dot4(wr[k], f4p[k]);
  gv[t] = acc;
  __syncthreads();
  if (t < 64){
    const int u2 = p*64 + t;
    const float iv = gv[t], fv = gv[64+t], gg = gv[128+t], ov = gv[192+t];
    const float c = sigm(fv)*cx[u2] + sigm(iv)*tanhf(gg);
    const float h = sigm(ov)*tanhf(c);
    out[5   + u2] = h;
    out[261 + u2] = c;
    hh[t] = h;
  }
  __syncthreads();
  if (t < 64){
    #pragma unroll
    for (int o=0;o<5;++o){
      const float* wrow = (o==0) ? cw : (acw + (o-1)*288);
      float pr = hh[t]*wrow[p*64 + t];
      #pragma unroll
      for (int off=32; off; off>>=1) pr += __shfl_down(pr, off, 64);
      if (t == 0) atomicAdd(out + o, pr);
    }
  }
}

extern "C" void kernel_launch(void* const* d_in, const int* in_sizes, int n_in,
                              void* d_out, int out_size, void* d_ws, size_t ws_size,
                              hipStream_t stream) {
  (void)in_sizes; (void)n_in; (void)out_size; (void)ws_size;
  const float* x    = (const float*)d_in[0];
  const int*   inst = (const int*)  d_in[1];
  const int*   tx   = (const int*)  d_in[2];
  const float* hx   = (const float*)d_in[3];
  const float* cx   = (const float*)d_in[4];
  const float* i1w  = (const float*)d_in[5];
  const float* i1b  = (const float*)d_in[6];
  const float* i2w  = (const float*)d_in[7];
  const float* i2b  = (const float*)d_in[8];
  const float* i3w  = (const float*)d_in[9];
  const float* i3b  = (const float*)d_in[10];
  const float* emb  = (const float*)d_in[11];
  const float* gwi  = (const float*)d_in[12];
  const float* gwh  = (const float*)d_in[13];
  const float* gbi  = (const float*)d_in[14];
  const float* gbh  = (const float*)d_in[15];
  const float* aw   = (const float*)d_in[16];
  const float* ab   = (const float*)d_in[17];
  const float* temb = (const float*)d_in[18];
  const float* lnw  = (const float*)d_in[19];
  const float* lnb  = (const float*)d_in[20];
  const float* lwi  = (const float*)d_in[21];
  const float* lwh  = (const float*)d_in[22];
  const float* lbi  = (const float*)d_in[23];
  const float* lbh  = (const float*)d_in[24];
  const float* cw   = (const float*)d_in[25];
  const float* cb   = (const float*)d_in[26];
  const float* acw  = (const float*)d_in[27];
  const float* acb  = (const float*)d_in[28];
  float* ws  = (float*)d_ws;
  float* out = (float*)d_out;

  a3c_pre <<<582, 256, 0, stream>>>(x, i1w, i1b, i2w, i2b, i3w, i3b,
                                    hx, lwh, lbh, tx, temb, cw, cb, acw, acb,
                                    inst, emb, gwi, gbi, gwh, ws, out);
  a3c_scan<<<1, 256, 0, stream>>>(gbh, aw, ab, lnw, lnb, ws);
  a3c_post<<<4, 256, 0, stream>>>(lwi, lbi, cx, cw, acw, ws, out);
}

// Round 14
// 144.274 us; speedup vs baseline: 1.3229x; 1.0832x over previous
//
#include <hip/hip_runtime.h>
#include <math.h>

// ---------------------------------------------------------------------------
// A3C_LSTM_GA forward, batch=1.  R14: single-CU GRU scan, THREE-TIER weights
// sized to the measured allocation law (grant = min(256, 2048/(2*wavesWG))):
//   512 threads (8 waves, grant 128/thread, 2 waves/SIMD for latency hiding)
//   thread t: j=t&1 col-half, u=t>>1; owns rows {u,256+u,512+u} x 128 cols
//   T1 regs: rel cols [0,64)   = 96 h2 VGPRs (under-grant -> resident, R1 law)
//   T2 LDS : rel cols [64,112) = 144 KB, [(c,j)][row] conflict-free b128
//   T3 L2  : rel cols [112,128) = 49 KB/step explicit reload (designed traffic)
// Halves combined via shfl_xor(1) (DPP); gate math thread-redundant; 2 barriers.
//  K1 a3c_pre (582 blocks x 256): b0 img MLP | b1-4 gates_h | b5 head-bias |
//     b6-197 gi f32 | b198-389 T1 pack | b390-533 T2 pack | b534-581 T3 pack
//  K2 a3c_scan (1 block x 512): scan + attention/fuse/lin tail
//  K3 a3c_post (4 blocks x 256): LSTM -> h/c -> head atomicAdd partials
// ---------------------------------------------------------------------------

typedef __fp16 h2 __attribute__((ext_vector_type(2)));
typedef __fp16 h8 __attribute__((ext_vector_type(8)));

// ws float offsets
#define WS_IMG    0        // 128
#define WS_GATESH 128      // 1024
#define WS_FUSED  1152     // 256
#define WS_GI     1408     // 64*768 f32                end 50560
#define WS_REGW   50560    // 49152 h2                  end 99712
#define WS_LDSW   99712    // 36864 h2                  end 136576
#define WS_STRW   136576   // 12288 h2                  end 148864

__device__ __forceinline__ float dot4(const float4 a, const float4 b){
  return a.x*b.x + a.y*b.y + a.z*b.z + a.w*b.w;
}
__device__ __forceinline__ float sigm(float x){ return 1.f/(1.f+expf(-x)); }

#define P0(v) __builtin_shufflevector(v,v,0,1)
#define P1(v) __builtin_shufflevector(v,v,2,3)
#define P2(v) __builtin_shufflevector(v,v,4,5)
#define P3(v) __builtin_shufflevector(v,v,6,7)
#define FD(w,e,acc) __builtin_amdgcn_fdot2(w,e,acc,false)

// ------------------------------------------------------------------- K1
__global__ __launch_bounds__(256) void a3c_pre(
    const float* __restrict__ x,
    const float* __restrict__ i1w, const float* __restrict__ i1b,
    const float* __restrict__ i2w, const float* __restrict__ i2b,
    const float* __restrict__ i3w, const float* __restrict__ i3b,
    const float* __restrict__ hx,  const float* __restrict__ lwh,
    const float* __restrict__ lbh,
    const int*   __restrict__ tx,  const float* __restrict__ temb,
    const float* __restrict__ cw,  const float* __restrict__ cb,
    const float* __restrict__ acw, const float* __restrict__ acb,
    const int*   __restrict__ inst, const float* __restrict__ emb,
    const float* __restrict__ gwi,  const float* __restrict__ gbi,
    const float* __restrict__ gwh,
    float* __restrict__ ws, float* __restrict__ out)
{
  const int b = blockIdx.x;
  const int t = threadIdx.x;

  if (b == 0) {
    // image MLP 400 -> 128 -> 128 -> 128
    __shared__ __align__(16) float x_lds[400];
    __shared__ __align__(16) float h1[128];
    __shared__ __align__(16) float h2s[128];
    x_lds[t] = x[t];
    if (t < 144) x_lds[256+t] = x[256+t];
    __syncthreads();
    {
      const int o = t>>1, half = t&1;
      const float4* wr = (const float4*)(i1w + o*400 + half*200);
      const float4* xr = (const float4*)(x_lds + half*200);
      float acc = 0.f;
      #pragma unroll 5
      for (int k=0;k<50;++k) acc += dot4(wr[k], xr[k]);
      acc += __shfl_down(acc, 1, 2);
      if (half == 0) h1[o] = fmaxf(acc + i1b[o], 0.f);
    }
    __syncthreads();
    if (t < 128){
      const float4* wr = (const float4*)(i2w + t*128);
      const float4* h4 = (const float4*)h1;
      float acc = i2b[t];
      #pragma unroll 8
      for (int k=0;k<32;++k) acc += dot4(wr[k], h4[k]);
      h2s[t] = fmaxf(acc, 0.f);
    }
    __syncthreads();
    if (t < 128){
      const float4* wr = (const float4*)(i3w + t*128);
      const float4* h4 = (const float4*)h2s;
      float acc = i3b[t];
      #pragma unroll 8
      for (int k=0;k<32;++k) acc += dot4(wr[k], h4[k]);
      ws[WS_IMG + t] = fmaxf(acc, 0.f);
    }

  } else if (b <= 4) {
    // gates_h = hx @ lstm_wh.T + lstm_bh
    __shared__ __align__(16) float hx_lds[256];
    hx_lds[t] = hx[t];
    __syncthreads();
    const int R = (b-1)*256 + t;
    const float4* wr = (const float4*)(lwh + R*256);
    const float4* h4 = (const float4*)hx_lds;
    float acc = lbh[R];
    #pragma unroll 8
    for (int k=0;k<64;++k) acc += dot4(wr[k], h4[k]);
    ws[WS_GATESH + R] = acc;

  } else if (b == 5) {
    // out[0..4] = bias + time-embedding partial of heads
    if (t < 64){
      float tv = 0.f;
      if (t < 32) tv = temb[tx[0]*32 + t];
      #pragma unroll
      for (int o=0;o<5;++o){
        const float* wrow = (o==0) ? cw : (acw + (o-1)*288);
        float pr = (t < 32) ? tv*wrow[256+t] : 0.f;
        #pragma unroll
        for (int off=16; off; off>>=1) pr += __shfl_down(pr, off, 32);
        if (t == 0) out[o] = pr + ((o==0) ? cb[0] : acb[o-1]);
      }
    }

  } else if (b < 198) {
    // gi[s][row] (f32): 192 blocks x 256 = 49152 = 64*768
    const int idx = (b-6)*256 + t;
    const int s = idx / 768;
    const int r = idx - s*768;
    const float4* wr = (const float4*)(gwi + r*32);
    const float4* er = (const float4*)(emb + inst[s]*32);
    float acc = gbi[r];
    #pragma unroll
    for (int k=0;k<8;++k) acc += dot4(wr[k], er[k]);
    ws[WS_GI + idx] = acc;

  } else if (b < 390) {
    // T1 regs pack: wr/wz/wn[c] = rsrc[(g*32+c)*512 + tt]
    const int d = (b-198)*256 + t;       // 0..49151
    const int g = d >> 14;
    const int rem = d & 16383;
    const int c = rem >> 9;
    const int tt = rem & 511;
    const int jj = tt & 1, uu = tt >> 1;
    const int row = g*256 + uu;
    const int col = jj*128 + 2*c;
    h2 v; v[0]=(__fp16)gwh[row*256+col]; v[1]=(__fp16)gwh[row*256+col+1];
    ((h2*)(ws + WS_REGW))[d] = v;

  } else if (b < 534) {
    // T2 LDS pack: 16B block bi = (c*2+j)*768 + row, h2 slot q = bi*4+e2
    const int q = (b-390)*256 + t;       // 0..36863
    const int bi = q >> 2, e2 = q & 3;
    const int c  = bi / 1536;
    const int rem = bi - c*1536;
    const int jj = rem / 768;
    const int row = rem - jj*768;
    const int col = jj*128 + 64 + 8*c + 2*e2;
    h2 v; v[0]=(__fp16)gwh[row*256+col]; v[1]=(__fp16)gwh[row*256+col+1];
    ((h2*)(ws + WS_LDSW))[q] = v;

  } else {
    // T3 stream pack: float4 fi = (g*2+e)*512 + tt
    const int q = (b-534)*256 + t;       // 0..12287
    const int fi = q >> 2, e2 = q & 3;
    const int ge = fi >> 9;
    const int tt = fi & 511;
    const int g = ge >> 1, e = ge & 1;
    const int jj = tt & 1, uu = tt >> 1;
    const int row = g*256 + uu;
    const int col = jj*128 + 112 + e*8 + 2*e2;
    h2 v; v[0]=(__fp16)gwh[row*256+col]; v[1]=(__fp16)gwh[row*256+col+1];
    ((h2*)(ws + WS_STRW))[q] = v;
  }
}

// ------------------------------------------------------------------- K2
__global__ __launch_bounds__(512) void a3c_scan(
    const float* __restrict__ gbh,
    const float* __restrict__ aw,  const float* __restrict__ ab,
    const float* __restrict__ lnw, const float* __restrict__ lnb,
    float* __restrict__ ws)
{
  const int t = threadIdx.x;
  const int j = t & 1, u = t >> 1;

  __shared__ __align__(16) __fp16 lw[6*2*768*8];    // 147456 B
  __shared__ __align__(16) __fp16 h16[256];
  __shared__ __align__(16) float h32[256];
  __shared__ __align__(16) float f0[128];

  // stage T2 (linear coalesced copy: 9216 float4)
  {
    const float4* lsrc = (const float4*)(ws + WS_LDSW);
    float4* ldst = (float4*)lw;
    #pragma unroll
    for (int n=0;n<18;++n) ldst[n*512+t] = lsrc[n*512+t];
  }
  // T1: 96 h2 regs, constant-unrolled arrays (R1-proven promotion)
  h2 wr[32], wz[32], wn[32];
  {
    const h2* rsrc = (const h2*)(ws + WS_REGW);
    #pragma unroll
    for (int c=0;c<32;++c) wr[c] = rsrc[(c   )*512 + t];
    #pragma unroll
    for (int c=0;c<32;++c) wz[c] = rsrc[(32+c)*512 + t];
    #pragma unroll
    for (int c=0;c<32;++c) wn[c] = rsrc[(64+c)*512 + t];
  }
  const float bh0 = gbh[u], bh1 = gbh[256+u], bh2 = gbh[512+u];
  float hprev = 0.f;
  if (t < 256){ h16[t] = (__fp16)0.f; h32[t] = 0.f; }
  __syncthreads();

  const float4* sp = (const float4*)(ws + WS_STRW);
  const __fp16* hb = h16 + 128*j;

  for (int s=0;s<64;++s){
    const float g0v = ws[WS_GI + s*768 +       u];
    const float g1v = ws[WS_GI + s*768 + 256 + u];
    const float g2v = ws[WS_GI + s*768 + 512 + u];
    // T3 stream (L2, 96 B/thread)
    const float4 s00 = sp[0*512+t], s01 = sp[1*512+t];
    const float4 s10 = sp[2*512+t], s11 = sp[3*512+t];
    const float4 s20 = sp[4*512+t], s21 = sp[5*512+t];

    float a0=0.f,b0_=0.f, a1=0.f,b1_=0.f, a2=0.f,b2_=0.f;
    // T1: rel cols [0,64)
    #pragma unroll
    for (int c=0;c<8;++c){
      const h8 hv = *(const h8*)(hb + 8*c);
      a0 =FD(wr[4*c  ],P0(hv),a0 ); b0_=FD(wr[4*c+1],P1(hv),b0_);
      a0 =FD(wr[4*c+2],P2(hv),a0 ); b0_=FD(wr[4*c+3],P3(hv),b0_);
      a1 =FD(wz[4*c  ],P0(hv),a1 ); b1_=FD(wz[4*c+1],P1(hv),b1_);
      a1 =FD(wz[4*c+2],P2(hv),a1 ); b1_=FD(wz[4*c+3],P3(hv),b1_);
      a2 =FD(wn[4*c  ],P0(hv),a2 ); b2_=FD(wn[4*c+1],P1(hv),b2_);
      a2 =FD(wn[4*c+2],P2(hv),a2 ); b2_=FD(wn[4*c+3],P3(hv),b2_);
    }
    // T2: rel cols [64,112), conflict-free b128
    #pragma unroll
    for (int c=0;c<6;++c){
      const h8 hv = *(const h8*)(hb + 64 + 8*c);
      const __fp16* base = lw + ((c*2 + j)*768)*8;
      const h8 u0 = *(const h8*)(base + u*8);
      const h8 u1 = *(const h8*)(base + (256+u)*8);
      const h8 u2 = *(const h8*)(base + (512+u)*8);
      a0 =FD(P0(u0),P0(hv),a0 ); b0_=FD(P1(u0),P1(hv),b0_);
      a0 =FD(P2(u0),P2(hv),a0 ); b0_=FD(P3(u0),P3(hv),b0_);
      a1 =FD(P0(u1),P0(hv),a1 ); b1_=FD(P1(u1),P1(hv),b1_);
      a1 =FD(P2(u1),P2(hv),a1 ); b1_=FD(P3(u1),P3(hv),b1_);
      a2 =FD(P0(u2),P0(hv),a2 ); b2_=FD(P1(u2),P1(hv),b2_);
      a2 =FD(P2(u2),P2(hv),a2 ); b2_=FD(P3(u2),P3(hv),b2_);
    }
    // T3: rel cols [112,128)
    {
      const h8 hv0 = *(const h8*)(hb + 112);
      const h8 hv1 = *(const h8*)(hb + 120);
      const h8 t00 = __builtin_bit_cast(h8, s00);
      const h8 t01 = __builtin_bit_cast(h8, s01);
      const h8 t10 = __builtin_bit_cast(h8, s10);
      const h8 t11 = __builtin_bit_cast(h8, s11);
      const h8 t20 = __builtin_bit_cast(h8, s20);
      const h8 t21 = __builtin_bit_cast(h8, s21);
      a0 =FD(P0(t00),P0(hv0),a0 ); b0_=FD(P1(t00),P1(hv0),b0_);
      a0 =FD(P2(t00),P2(hv0),a0 ); b0_=FD(P3(t00),P3(hv0),b0_);
      a0 =FD(P0(t01),P0(hv1),a0 ); b0_=FD(P1(t01),P1(hv1),b0_);
      a0 =FD(P2(t01),P2(hv1),a0 ); b0_=FD(P3(t01),P3(hv1),b0_);
      a1 =FD(P0(t10),P0(hv0),a1 ); b1_=FD(P1(t10),P1(hv0),b1_);
      a1 =FD(P2(t10),P2(hv0),a1 ); b1_=FD(P3(t10),P3(hv0),b1_);
      a1 =FD(P0(t11),P0(hv1),a1 ); b1_=FD(P1(t11),P1(hv1),b1_);
      a1 =FD(P2(t11),P2(hv1),a1 ); b1_=FD(P3(t11),P3(hv1),b1_);
      a2 =FD(P0(t20),P0(hv0),a2 ); b2_=FD(P1(t20),P1(hv0),b2_);
      a2 =FD(P2(t20),P2(hv0),a2 ); b2_=FD(P3(t20),P3(hv0),b2_);
      a2 =FD(P0(t21),P0(hv1),a2 ); b2_=FD(P1(t21),P1(hv1),b2_);
      a2 =FD(P2(t21),P2(hv1),a2 ); b2_=FD(P3(t21),P3(hv1),b2_);
    }

    float r_ = a0 + b0_, z_ = a1 + b1_, n_ = a2 + b2_;
    r_ += __shfl_xor(r_, 1);
    z_ += __shfl_xor(z_, 1);
    n_ += __shfl_xor(n_, 1);
    const float rr = sigm(g0v + r_ + bh0);
    const float zz = sigm(g1v + z_ + bh1);
    const float nn = tanhf(g2v + rr*(n_ + bh2));
    const float hv_ = (1.f - zz)*nn + zz*hprev;
    hprev = hv_;
    __syncthreads();                   // all h16 reads complete
    if (j == 0){ h32[u] = hv_; h16[u] = (__fp16)hv_; }
    __syncthreads();
  }

  // ---------------- attention -> fuse -> lin (h_enc == h32)
  if (t < 128){
    const float4* wrp = (const float4*)(aw + t*256);
    const float4* h4 = (const float4*)h32;
    float acc = ab[t];
    #pragma unroll 8
    for (int k=0;k<64;++k) acc += dot4(wrp[k], h4[k]);
    f0[t] = ws[WS_IMG + t] * sigm(acc);
  }
  __syncthreads();
  if (t < 256){
    const float4* wrp = (const float4*)(lnw + t*128);
    const float4* h4 = (const float4*)f0;
    float acc = lnb[t];
    #pragma unroll 8
    for (int k=0;k<32;++k) acc += dot4(wrp[k], h4[k]);
    ws[WS_FUSED + t] = fmaxf(acc, 0.f);
  }
}

// ------------------------------------------------------------------- K3
__global__ __launch_bounds__(256) void a3c_post(
    const float* __restrict__ lwi, const float* __restrict__ lbi,
    const float* __restrict__ cx,
    const float* __restrict__ cw,  const float* __restrict__ acw,
    float* __restrict__ ws, float* __restrict__ out)
{
  const int p = blockIdx.x;            // 0..3, owns 64 LSTM units
  const int t = threadIdx.x;
  __shared__ __align__(16) float fused_lds[256];
  __shared__ float gv[256];
  __shared__ float hh[64];
  fused_lds[t] = ws[WS_FUSED + t];
  __syncthreads();
  const int g = t>>6, ul = t&63;
  const int R = (g<<8) + p*64 + ul;
  const float4* wrp = (const float4*)(lwi + R*256);
  const float4* f4p = (const float4*)fused_lds;
  float acc = ws[WS_GATESH + R] + lbi[R];
  #pragma unroll 8
  for (int k=0;k<64;++k) acc += dot4(wrp[k], f4p[k]);
  gv[t] = acc;
  __syncthreads();
  if (t < 64){
    const int u2 = p*64 + t;
    const float iv = gv[t], fv = gv[64+t], gg = gv[128+t], ov = gv[192+t];
    const float c = sigm(fv)*cx[u2] + sigm(iv)*tanhf(gg);
    const float h = sigm(ov)*tanhf(c);
    out[5   + u2] = h;
    out[261 + u2] = c;
    hh[t] = h;
  }
  __syncthreads();
  if (t < 64){
    #pragma unroll
    for (int o=0;o<5;++o){
      const float* wrow = (o==0) ? cw : (acw + (o-1)*288);
      float pr = hh[t]*wrow[p*64 + t];
      #pragma unroll
      for (int off=32; off; off>>=1) pr += __shfl_down(pr, off, 64);
      if (t == 0) atomicAdd(out + o, pr);
    }
  }
}

extern "C" void kernel_launch(void* const* d_in, const int* in_sizes, int n_in,
                              void* d_out, int out_size, void* d_ws, size_t ws_size,
                              hipStream_t stream) {
  (void)in_sizes; (void)n_in; (void)out_size; (void)ws_size;
  const float* x    = (const float*)d_in[0];
  const int*   inst = (const int*)  d_in[1];
  const int*   tx   = (const int*)  d_in[2];
  const float* hx   = (const float*)d_in[3];
  const float* cx   = (const float*)d_in[4];
  const float* i1w  = (const float*)d_in[5];
  const float* i1b  = (const float*)d_in[6];
  const float* i2w  = (const float*)d_in[7];
  const float* i2b  = (const float*)d_in[8];
  const float* i3w  = (const float*)d_in[9];
  const float* i3b  = (const float*)d_in[10];
  const float* emb  = (const float*)d_in[11];
  const float* gwi  = (const float*)d_in[12];
  const float* gwh  = (const float*)d_in[13];
  const float* gbi  = (const float*)d_in[14];
  const float* gbh  = (const float*)d_in[15];
  const float* aw   = (const float*)d_in[16];
  const float* ab   = (const float*)d_in[17];
  const float* temb = (const float*)d_in[18];
  const float* lnw  = (const float*)d_in[19];
  const float* lnb  = (const float*)d_in[20];
  const float* lwi  = (const float*)d_in[21];
  const float* lwh  = (const float*)d_in[22];
  const float* lbi  = (const float*)d_in[23];
  const float* lbh  = (const float*)d_in[24];
  const float* cw   = (const float*)d_in[25];
  const float* cb   = (const float*)d_in[26];
  const float* acw  = (const float*)d_in[27];
  const float* acb  = (const float*)d_in[28];
  float* ws  = (float*)d_ws;
  float* out = (float*)d_out;

  a3c_pre <<<582, 256, 0, stream>>>(x, i1w, i1b, i2w, i2b, i3w, i3b,
                                    hx, lwh, lbh, tx, temb, cw, cb, acw, acb,
                                    inst, emb, gwi, gbi, gwh, ws, out);
  a3c_scan<<<1, 512, 0, stream>>>(gbh, aw, ab, lnw, lnb, ws);
  a3c_post<<<4, 256, 0, stream>>>(lwi, lbi, cx, cw, acw, ws, out);
}